// Round 6
// baseline (115.906 us; speedup 1.0000x reference)
//
#include <hip/hip_runtime.h>
#include <math.h>

#define NUM_CLASSES 10

typedef __attribute__((ext_vector_type(2))) float f32x2;

// ---- block reduction: wave shuffle (64) -> LDS across waves -> lane 0 ----
__device__ __forceinline__ double block_reduce_sum(double v, double* lds) {
    #pragma unroll
    for (int off = 32; off > 0; off >>= 1)
        v += __shfl_down(v, off, 64);
    int lane = threadIdx.x & 63;
    int wid  = threadIdx.x >> 6;
    int nw   = blockDim.x >> 6;
    if (lane == 0) lds[wid] = v;
    __syncthreads();
    if (wid == 0) {
        v = (lane < nw) ? lds[lane] : 0.0;
        #pragma unroll
        for (int off = 4; off > 0; off >>= 1)
            v += __shfl_down(v, off, 64);
    }
    return v;
}

__device__ __forceinline__ double focal_term(
    const float* __restrict__ logits, const int* __restrict__ targets,
    const int* __restrict__ tissue, const float* __restrict__ cw,
    const float* __restrict__ tw, int r) {
    const float* row = logits + (size_t)r * NUM_CLASSES;
    float l[NUM_CLASSES];
    float m = -INFINITY;
    #pragma unroll
    for (int c = 0; c < NUM_CLASSES; ++c) { l[c] = row[c]; m = fmaxf(m, l[c]); }
    float s = 0.f;
    #pragma unroll
    for (int c = 0; c < NUM_CLASSES; ++c) s += expf(l[c] - m);
    int   t  = targets[r];
    float lp = l[t] - m - logf(s);
    float p  = expf(lp);
    float om = 1.f - p;
    float w  = om * om * cw[t] * tw[tissue[r]];
    return (double)(-w * lp);
}

// 4 fp8 pairs (packed in two ints) -> fp32 dot accumulate
__device__ __forceinline__ float fp8dot4(int a, int b, float d) {
    f32x2 al = __builtin_amdgcn_cvt_pk_f32_fp8(a, false);
    f32x2 ah = __builtin_amdgcn_cvt_pk_f32_fp8(a, true);
    f32x2 bl = __builtin_amdgcn_cvt_pk_f32_fp8(b, false);
    f32x2 bh = __builtin_amdgcn_cvt_pk_f32_fp8(b, true);
    d = fmaf(al.x, bl.x, d); d = fmaf(al.y, bl.y, d);
    d = fmaf(ah.x, bh.x, d); d = fmaf(ah.y, bh.y, d);
    return d;
}

__device__ __forceinline__ float fp8dot16(int4 a, int4 b) {
    float dot = 0.f;
    dot = fp8dot4(a.x, b.x, dot);
    dot = fp8dot4(a.y, b.y, dot);
    dot = fp8dot4(a.z, b.z, dot);
    dot = fp8dot4(a.w, b.w, dot);
    return dot;
}

// ---- pack: node record = 64 B line: relu(S) fp8 e4m3 [32 B] + pos [8 B] + pad
__global__ void pack_kernel(const float4* __restrict__ S4,
                            const float2* __restrict__ pos,
                            int* __restrict__ rec_i,
                            int n4, int N) {
    int i = blockIdx.x * blockDim.x + threadIdx.x;
    if (i < n4) {
        float4 v = S4[i];
        int w = __builtin_amdgcn_cvt_pk_fp8_f32(fmaxf(v.x, 0.f), fmaxf(v.y, 0.f), 0, false);
        w = __builtin_amdgcn_cvt_pk_fp8_f32(fmaxf(v.z, 0.f), fmaxf(v.w, 0.f), w, true);
        int node = i >> 3, sub = i & 7;
        rec_i[node * 16 + sub] = w;
    }
    if (i < N) {
        float2 p = pos[i];
        rec_i[i * 16 + 8] = __float_as_int(p.x);
        rec_i[i * 16 + 9] = __float_as_int(p.y);
    }
}

#define EPT 4   // edges per lane-pair

// ---- main kernel: 2 lanes cooperate per edge; lane p loads 16 B half p of
//      both records + its own node's pos (same line). All loads batched.
__global__ __launch_bounds__(256) void spatial_focal_kernel(
    const float* __restrict__ logits,
    const int*   __restrict__ targets,
    const int*   __restrict__ tissue,
    const float* __restrict__ cw,
    const float* __restrict__ tw,
    const int4*  __restrict__ rec,     // 4 int4 per node (64 B records)
    const int*   __restrict__ src_idx,
    const int*   __restrict__ dst_idx,
    int B, int E, int G,               // G = total lane-pairs
    double*      __restrict__ part_f,
    double*      __restrict__ part_s) {

    __shared__ double lds_f[4];
    __shared__ double lds_s[4];
    int gtid = blockIdx.x * blockDim.x + threadIdx.x;

    double fl = 0.0;
    if (gtid < B) fl = focal_term(logits, targets, tissue, cw, tw, gtid);

    int p = gtid & 1;                  // 0 = src-side lane, 1 = dst-side lane
    int g = gtid >> 1;                 // pair id
    const int* mybase = p ? dst_idx : src_idx;

    int   ec[EPT];
    float msk[EPT];
    #pragma unroll
    for (int j = 0; j < EPT; ++j) {
        int e  = g + j * G;
        msk[j] = (e < E) ? 1.f : 0.f;
        ec[j]  = (e < E) ? e : 0;
    }

    // --- my-side index loads (even lanes: src stream, odd lanes: dst stream)
    int mine[EPT];
    #pragma unroll
    for (int j = 0; j < EPT; ++j) mine[j] = mybase[ec[j]];

    // --- exchange with partner lane -> both lanes hold (s, d)
    int s_[EPT], d_[EPT];
    #pragma unroll
    for (int j = 0; j < EPT; ++j) {
        int other = __shfl_xor(mine[j], 1, 64);
        s_[j] = p ? other  : mine[j];
        d_[j] = p ? mine[j] : other;
    }

    // --- all gathers batched: my 16 B half of src row + dst row, my pos ---
    int4   rs[EPT], rd[EPT];
    float2 pm[EPT];
    #pragma unroll
    for (int j = 0; j < EPT; ++j) {
        const int4* qs = rec + (size_t)s_[j] * 4;
        const int4* qd = rec + (size_t)d_[j] * 4;
        rs[j] = qs[p];                         // halves of the SAME line merge
        rd[j] = qd[p];                         //   across the lane pair
        pm[j] = *(const float2*)((p ? qd : qs) + 2);   // my node's pos (same line)
    }

    // --- compute ---
    double sp = 0.0;
    #pragma unroll
    for (int j = 0; j < EPT; ++j) {
        float dh  = fp8dot16(rs[j], rd[j]);            // my half of the dot
        float dot = dh + __shfl_xor(dh, 1, 64);        // full 32-wide dot
        float ox  = __shfl_xor(pm[j].x, 1, 64);        // partner node's pos
        float oy  = __shfl_xor(pm[j].y, 1, 64);
        float dx  = pm[j].x - ox;
        float dy  = pm[j].y - oy;                      // sign-symmetric, d2 same
        sp += (double)(msk[j] * dot * (dx * dx + dy * dy));
    }
    sp *= 0.5;                                         // both lanes accumulated

    double bs_f = block_reduce_sum(fl, lds_f);
    double bs_s = block_reduce_sum(sp, lds_s);
    if (threadIdx.x == 0) {
        part_f[blockIdx.x] = bs_f;
        part_s[blockIdx.x] = bs_s;
    }
}

// ---- final reduce: one block sums the per-block partials ----
__global__ void reduce_kernel(const double* __restrict__ part_f,
                              const double* __restrict__ part_s,
                              int nb, float* __restrict__ out, int B, int E) {
    __shared__ double lds_f[4];
    __shared__ double lds_s[4];
    double f = 0.0, s = 0.0;
    for (int i = threadIdx.x; i < nb; i += blockDim.x) {
        f += part_f[i];
        s += part_s[i];
    }
    double tf = block_reduce_sum(f, lds_f);
    double ts = block_reduce_sum(s, lds_s);
    if (threadIdx.x == 0) {
        float cls = (float)(tf / (double)B);
        float spv = (float)(0.01 * ts / (double)E);
        out[0] = cls + spv;
        out[1] = cls;
        out[2] = spv;
    }
}

// ---- fallback: fp32 direct (only if ws can't hold rec + partials) ----
__global__ __launch_bounds__(256) void fallback_kernel(
    const float*  __restrict__ logits,
    const int*    __restrict__ targets,
    const int*    __restrict__ tissue,
    const float*  __restrict__ cw,
    const float*  __restrict__ tw,
    const float4* __restrict__ S4,
    const float2* __restrict__ pos,
    const int*    __restrict__ src_idx,
    const int*    __restrict__ dst_idx,
    int B, int E, int T,
    double*       __restrict__ part_f,
    double*       __restrict__ part_s) {
    __shared__ double lds_f[4];
    __shared__ double lds_s[4];
    int gtid = blockIdx.x * blockDim.x + threadIdx.x;
    double fl = 0.0;
    if (gtid < B) fl = focal_term(logits, targets, tissue, cw, tw, gtid);
    double sp = 0.0;
    for (int e = gtid; e < E; e += T) {
        int s = src_idx[e], d = dst_idx[e];
        const float4* Sr = S4 + (size_t)s * 8;
        const float4* Dr = S4 + (size_t)d * 8;
        float dot = 0.f;
        #pragma unroll
        for (int c = 0; c < 8; ++c) {
            float4 a = Sr[c], b = Dr[c];
            dot += fmaxf(a.x, 0.f) * fmaxf(b.x, 0.f);
            dot += fmaxf(a.y, 0.f) * fmaxf(b.y, 0.f);
            dot += fmaxf(a.z, 0.f) * fmaxf(b.z, 0.f);
            dot += fmaxf(a.w, 0.f) * fmaxf(b.w, 0.f);
        }
        float2 pp = pos[s], qq = pos[d];
        float dx = pp.x - qq.x, dy = pp.y - qq.y;
        sp += (double)(dot * (dx * dx + dy * dy));
    }
    double bs_f = block_reduce_sum(fl, lds_f);
    double bs_s = block_reduce_sum(sp, lds_s);
    if (threadIdx.x == 0) {
        part_f[blockIdx.x] = bs_f;
        part_s[blockIdx.x] = bs_s;
    }
}

extern "C" void kernel_launch(void* const* d_in, const int* in_sizes, int n_in,
                              void* d_out, int out_size, void* d_ws, size_t ws_size,
                              hipStream_t stream) {
    const float* logits  = (const float*)d_in[0];
    const int*   targets = (const int*)  d_in[1];
    const float* S       = (const float*)d_in[2];
    const float* pos     = (const float*)d_in[3];
    const int*   edge    = (const int*)  d_in[4];
    const int*   tissue  = (const int*)  d_in[5];
    const float* cw      = (const float*)d_in[6];
    const float* tw      = (const float*)d_in[7];
    float* out = (float*)d_out;

    int B  = in_sizes[1];
    int E  = in_sizes[4] / 2;
    int nS = in_sizes[2];            // N * 32
    int N  = in_sizes[3] / 2;        // nodes
    int n4 = nS / 4;

    // 128 lane-pairs per block, EPT edges per pair -> 512 edges per block
    int nb = (E + 128 * EPT - 1) / (128 * EPT);   // 3125 for E = 1.6M
    int G  = nb * 128;                            // total lane-pairs

    size_t rec_bytes = (size_t)N * 64;
    size_t part_off  = (rec_bytes + 255) & ~(size_t)255;
    size_t need      = part_off + (size_t)2 * nb * sizeof(double) + 256;

    if (ws_size >= need) {
        int*    rec    = (int*)d_ws;
        double* part_f = (double*)((char*)d_ws + part_off);
        double* part_s = part_f + nb;
        int packN = (n4 > N) ? n4 : N;
        pack_kernel<<<(packN + 255) / 256, 256, 0, stream>>>(
            (const float4*)S, (const float2*)pos, rec, n4, N);
        spatial_focal_kernel<<<nb, 256, 0, stream>>>(
            logits, targets, tissue, cw, tw,
            (const int4*)rec, edge, edge + E,
            B, E, G, part_f, part_s);
        reduce_kernel<<<1, 256, 0, stream>>>(part_f, part_s, nb, out, B, E);
    } else {
        int nb2 = 2048;
        int T2  = nb2 * 256;
        double* part_f = (double*)d_ws;
        double* part_s = part_f + nb2;
        fallback_kernel<<<nb2, 256, 0, stream>>>(
            logits, targets, tissue, cw, tw,
            (const float4*)S, (const float2*)pos, edge, edge + E,
            B, E, T2, part_f, part_s);
        reduce_kernel<<<1, 256, 0, stream>>>(part_f, part_s, nb2, out, B, E);
    }
}